// Round 1
// baseline (1502.813 us; speedup 1.0000x reference)
//
#include <hip/hip_runtime.h>
#include <hip/hip_fp16.h>

using half8 = __attribute__((ext_vector_type(8))) _Float16;
using f32x4 = __attribute__((ext_vector_type(4))) float;

union V16 { uint4 u; half8 h; };

__device__ __forceinline__ ushort f2h_bits(float f) {
  return __half_as_ushort(__float2half(f));
}
__device__ __forceinline__ float h2f_lo(unsigned u) {
  return __half2float(__ushort_as_half((ushort)(u & 0xffffu)));
}
__device__ __forceinline__ float h2f_hi(unsigned u) {
  return __half2float(__ushort_as_half((ushort)(u >> 16)));
}

// ---------------------------------------------------------------------------
// prep: W1 [1024,256] fp32 -> W1T [256,1024] fp16; zero stats[512]; bag offsets
// ---------------------------------------------------------------------------
__global__ void prep_kernel(const float* __restrict__ W1,
                            const void* __restrict__ bag_sizes,
                            ushort* __restrict__ W1T,
                            float* __restrict__ stats,
                            int* __restrict__ off,
                            int n, int nb, int w1elems) {
  long g = (long)blockIdx.x * 256 + threadIdx.x;
  if (g < w1elems) {
    int k = (int)(g >> 8);      // d_in index
    int nn = (int)(g & 255);    // d_hid index
    W1T[nn * 1024 + k] = f2h_bits(W1[g]);
  }
  if (g < 512) stats[g] = 0.f;
  if (g == 0) {
    // bag_sizes may be int32 (jax default) or int64; autodetect via sum == n
    const int* b32 = (const int*)bag_sizes;
    long s = 0;
    for (int i = 0; i < nb; ++i) s += b32[i];
    const long long* b64 = (const long long*)bag_sizes;
    int use64 = (s != (long)n);
    int acc = 0;
    off[0] = 0;
    for (int i = 0; i < nb; ++i) {
      int sz = use64 ? (int)b64[i] : b32[i];
      acc += sz;
      off[i + 1] = acc;
    }
  }
}

// ---------------------------------------------------------------------------
// gemm1: h = features @ W1 + b1, fp16 MFMA, h stored fp16 [n,256]
// tile 64(M) x 256(N) x 64(K), 256 threads = 4 waves, wave tile 64x64
// ---------------------------------------------------------------------------
__global__ __launch_bounds__(256, 3) void gemm1_kernel(
    const float* __restrict__ A,   // [n,1024] fp32
    const ushort* __restrict__ BT, // [256,1024] fp16 (W1 transposed)
    const float* __restrict__ b1,  // [256]
    ushort* __restrict__ H,        // [n,256] fp16 out
    int n) {
  __shared__ __align__(16) char smem[40960]; // As 8KB + Bs 32KB; reused as bounce
  uint4* AsU = (uint4*)smem;                 // 64x64 fp16, 8-elem chunks, XOR swizzle
  uint4* BsU = (uint4*)(smem + 8192);        // 256x64 fp16 (n-major), XOR swizzle

  const int t = threadIdx.x;
  const int lane = t & 63;
  const int w = t >> 6;       // wave id 0..3 -> col block
  const int lid = lane & 15;
  const int quad = lane >> 4; // 0..3
  const long rowBase = (long)blockIdx.x * 64;

  f32x4 acc[4][4] = {};

  for (int k0 = 0; k0 < 1024; k0 += 64) {
    __syncthreads();
    // stage A: 64 rows x 64 k, fp32 -> fp16, 2 iters x 256 thr x 8 elems
#pragma unroll
    for (int i = 0; i < 2; ++i) {
      int cid = i * 256 + t;
      int m = cid >> 3, kc = cid & 7;
      long row = rowBase + m;
      if (row >= n) row = n - 1;
      const float4* gp = (const float4*)(A + row * 1024 + k0 + kc * 8);
      float4 f0 = gp[0], f1 = gp[1];
      uint4 u;
      u.x = (unsigned)f2h_bits(f0.x) | ((unsigned)f2h_bits(f0.y) << 16);
      u.y = (unsigned)f2h_bits(f0.z) | ((unsigned)f2h_bits(f0.w) << 16);
      u.z = (unsigned)f2h_bits(f1.x) | ((unsigned)f2h_bits(f1.y) << 16);
      u.w = (unsigned)f2h_bits(f1.z) | ((unsigned)f2h_bits(f1.w) << 16);
      AsU[m * 8 + (kc ^ (m & 7))] = u;
    }
    // stage B: 256 n x 64 k fp16 copy, 8 iters
#pragma unroll
    for (int i = 0; i < 8; ++i) {
      int cid = i * 256 + t;
      int nn = cid >> 3, kc = cid & 7;
      uint4 u = *(const uint4*)(BT + (size_t)nn * 1024 + k0 + kc * 8);
      BsU[nn * 8 + (kc ^ (nn & 7))] = u;
    }
    __syncthreads();
#pragma unroll
    for (int kq = 0; kq < 2; ++kq) {
      half8 fa[4], fb[4];
#pragma unroll
      for (int mi = 0; mi < 4; ++mi) {
        int m = mi * 16 + lid;
        V16 v; v.u = AsU[m * 8 + ((kq * 4 + quad) ^ (m & 7))];
        fa[mi] = v.h;
      }
#pragma unroll
      for (int ni = 0; ni < 4; ++ni) {
        int nn = w * 64 + ni * 16 + lid;
        V16 v; v.u = BsU[nn * 8 + ((kq * 4 + quad) ^ (nn & 7))];
        fb[ni] = v.h;
      }
#pragma unroll
      for (int mi = 0; mi < 4; ++mi)
#pragma unroll
        for (int ni = 0; ni < 4; ++ni)
          acc[mi][ni] = __builtin_amdgcn_mfma_f32_16x16x32_f16(
              fa[mi], fb[ni], acc[mi][ni], 0, 0, 0);
    }
  }
  __syncthreads();
  // epilogue: + b1, fp16, bounce through LDS for coalesced 16B stores
  ushort* bounce = (ushort*)smem; // 64x256 fp16 = 32KB
  float bv[4];
#pragma unroll
  for (int ni = 0; ni < 4; ++ni) bv[ni] = b1[w * 64 + ni * 16 + lid];
#pragma unroll
  for (int mi = 0; mi < 4; ++mi)
#pragma unroll
    for (int ni = 0; ni < 4; ++ni)
#pragma unroll
      for (int r = 0; r < 4; ++r) {
        int row = mi * 16 + quad * 4 + r;          // C/D: row=(lane>>4)*4+reg
        int col = w * 64 + ni * 16 + lid;          // col=lane&15
        bounce[row * 256 + col] = f2h_bits(acc[mi][ni][r] + bv[ni]);
      }
  __syncthreads();
  const uint4* bU = (const uint4*)smem;
#pragma unroll
  for (int i = 0; i < 8; ++i) {
    int cid = i * 256 + t;
    int row = cid >> 5, cc = cid & 31;
    long grow = rowBase + row;
    if (grow < n) *(uint4*)(H + grow * 256 + cc * 8) = bU[row * 32 + cc];
  }
}

// ---------------------------------------------------------------------------
// colstats: per-column sum and sumsq of h (fp16), atomics into stats[512]
// ---------------------------------------------------------------------------
__global__ __launch_bounds__(256) void colstats_kernel(
    const ushort* __restrict__ H, float* __restrict__ stats, int n) {
  __shared__ float red[2][8][256];
  const int t = threadIdx.x;
  const int cg = t & 31, rs = t >> 5;
  const int rowsPerBlock = n >> 8; // 256 blocks
  const long rbase = (long)blockIdx.x * rowsPerBlock;
  float s[8], q[8];
#pragma unroll
  for (int j = 0; j < 8; ++j) { s[j] = 0.f; q[j] = 0.f; }
  const int iters = rowsPerBlock >> 3;
  for (int i = 0; i < iters; ++i) {
    long r = rbase + i * 8 + rs;
    uint4 u = *(const uint4*)(H + r * 256 + cg * 8);
    unsigned uu[4] = {u.x, u.y, u.z, u.w};
#pragma unroll
    for (int p = 0; p < 4; ++p) {
      float x0 = h2f_lo(uu[p]), x1 = h2f_hi(uu[p]);
      s[2 * p] += x0;     q[2 * p] += x0 * x0;
      s[2 * p + 1] += x1; q[2 * p + 1] += x1 * x1;
    }
  }
#pragma unroll
  for (int j = 0; j < 8; ++j) {
    red[0][rs][cg * 8 + j] = s[j];
    red[1][rs][cg * 8 + j] = q[j];
  }
  __syncthreads();
  float ss = 0.f, qq = 0.f;
#pragma unroll
  for (int rr = 0; rr < 8; ++rr) { ss += red[0][rr][t]; qq += red[1][rr][t]; }
  atomicAdd(&stats[t], ss);
  atomicAdd(&stats[256 + t], qq);
}

// ---------------------------------------------------------------------------
// finalize: BN folded into per-col affine a,c; copy w2. (b2 cancels in softmax)
// ---------------------------------------------------------------------------
__global__ void finalize_kernel(const float* __restrict__ stats,
                                const float* __restrict__ gamma,
                                const float* __restrict__ beta,
                                const float* __restrict__ W2,
                                float* __restrict__ acw, float inv_n) {
  int t = threadIdx.x; // 256
  float mean = stats[t] * inv_n;
  float var = stats[256 + t] * inv_n - mean * mean;
  float inv = rsqrtf(var + 1e-5f);
  float a = gamma[t] * inv;
  acw[t] = a;
  acw[256 + t] = beta[t] - mean * a;
  acw[512 + t] = W2[t];
}

// ---------------------------------------------------------------------------
// scores: per row, s = sum_col relu(a*h + c) * w2
// ---------------------------------------------------------------------------
__global__ __launch_bounds__(256) void scores_kernel(
    const ushort* __restrict__ H, const float* __restrict__ acw,
    float* __restrict__ scores, int n) {
  __shared__ float sa[256], sc[256], sw[256];
  const int t = threadIdx.x;
  sa[t] = acw[t];
  sc[t] = acw[256 + t];
  sw[t] = acw[512 + t];
  __syncthreads();
  long r = (long)blockIdx.x * 256 + t;
  if (r >= n) return;
  float s = 0.f;
#pragma unroll 4
  for (int ch = 0; ch < 32; ++ch) {
    uint4 u = *(const uint4*)(H + r * 256 + ch * 8);
    unsigned uu[4] = {u.x, u.y, u.z, u.w};
#pragma unroll
    for (int p = 0; p < 4; ++p) {
      int c0 = ch * 8 + p * 2;
      float x0 = h2f_lo(uu[p]), x1 = h2f_hi(uu[p]);
      s += fmaxf(fmaf(sa[c0], x0, sc[c0]), 0.f) * sw[c0];
      s += fmaxf(fmaf(sa[c0 + 1], x1, sc[c0 + 1]), 0.f) * sw[c0 + 1];
    }
  }
  scores[r] = s;
}

// ---------------------------------------------------------------------------
// softmax: one block per bag, 3-phase (max, sumexp, write)
// ---------------------------------------------------------------------------
__global__ __launch_bounds__(256) void softmax_kernel(
    const float* __restrict__ scores, const int* __restrict__ off,
    float* __restrict__ out) {
  const int b = blockIdx.x;
  const int start = off[b], end = off[b + 1];
  const int t = threadIdx.x;
  const int lane = t & 63, wid = t >> 6;
  __shared__ float red[8];
  float m = -INFINITY;
  for (int r = start + t; r < end; r += 256) m = fmaxf(m, scores[r]);
#pragma unroll
  for (int o = 32; o; o >>= 1) m = fmaxf(m, __shfl_xor(m, o));
  if (lane == 0) red[wid] = m;
  __syncthreads();
  if (t == 0)
    red[0] = fmaxf(fmaxf(red[0], red[1]), fmaxf(red[2], red[3]));
  __syncthreads();
  m = red[0];
  float z = 0.f;
  for (int r = start + t; r < end; r += 256) z += __expf(scores[r] - m);
#pragma unroll
  for (int o = 32; o; o >>= 1) z += __shfl_xor(z, o);
  if (lane == 0) red[4 + wid] = z;
  __syncthreads();
  z = red[4] + red[5] + red[6] + red[7];
  float invz = 1.0f / z;
  for (int r = start + t; r < end; r += 256)
    out[r] = __expf(scores[r] - m) * invz;
}

// ---------------------------------------------------------------------------
extern "C" void kernel_launch(void* const* d_in, const int* in_sizes, int n_in,
                              void* d_out, int out_size, void* d_ws,
                              size_t ws_size, hipStream_t stream) {
  const float* features = (const float*)d_in[0];
  const void* bag_sizes = d_in[1];
  const float* W1 = (const float*)d_in[2];
  const float* b1 = (const float*)d_in[3];
  const float* gamma = (const float*)d_in[4];
  const float* beta = (const float*)d_in[5];
  const float* W2 = (const float*)d_in[6];
  // d_in[7] = b2: cancels inside per-bag softmax, unused.

  const int n = in_sizes[0] / 1024;  // rows (262144)
  const int nb = in_sizes[1];        // bags (128)
  const int w1elems = in_sizes[2];   // 262144

  char* ws = (char*)d_ws;
  ushort* W1T = (ushort*)ws;                               // 512 KB fp16
  ushort* H = (ushort*)(ws + 524288);                      // n*256 fp16 = 134 MB
  float* stats = (float*)(ws + 524288 + (size_t)n * 512);  // 512 fp32
  float* acw = stats + 512;                                // 768 fp32
  float* scores = acw + 768;                               // n fp32
  int* off = (int*)(scores + n);                           // nb+1 ints

  prep_kernel<<<(w1elems + 255) / 256, 256, 0, stream>>>(
      W1, bag_sizes, W1T, stats, off, n, nb, w1elems);
  gemm1_kernel<<<(n + 63) / 64, 256, 0, stream>>>(features, W1T, b1, H, n);
  colstats_kernel<<<256, 256, 0, stream>>>(H, stats, n);
  finalize_kernel<<<1, 256, 0, stream>>>(stats, gamma, beta, W2, acw,
                                         1.0f / (float)n);
  scores_kernel<<<(n + 255) / 256, 256, 0, stream>>>(H, acw, scores, n);
  softmax_kernel<<<nb, 256, 0, stream>>>(scores, off, (float*)d_out);
}